// Round 10
// baseline (125.035 us; speedup 1.0000x reference)
//
#include <hip/hip_runtime.h>
#include <cstdint>
#include <cstddef>

typedef __attribute__((ext_vector_type(4))) float f32x4;
typedef __attribute__((ext_vector_type(8))) short bf16x8;
typedef __attribute__((ext_vector_type(4))) short bf16x4;
typedef __attribute__((ext_vector_type(2))) short bf16x2;

#define DEVI static __device__ __forceinline__

DEVI short f2bf(float f){
  union { float f; uint32_t u; } v; v.f = f;
  uint32_t r = v.u + 0x7FFFu + ((v.u >> 16) & 1u);
  return (short)(r >> 16);
}
DEVI float bf2f(short h){
  union { uint32_t u; float f; } v; v.u = ((uint32_t)(uint16_t)h) << 16;
  return v.f;
}
DEVI float eluf(float x){ return x > 0.f ? x : (__expf(x) - 1.f); }
DEVI float sigm(float x){ return 1.f / (1.f + __expf(-x)); }

static constexpr int NPIX = 8 * 1024;   // B*S pixels

// ---- workspace layout (bytes) ----
static constexpr size_t SZ_W   = (size_t)983040 * 2;        // 3 x (w1 64K + w2 128K + wn 128K shorts), row-major
static constexpr size_t SZ_ACT = (size_t)NPIX * 256 * 2;    // 4 MiB bf16
static constexpr size_t OFF_W   = 0;
static constexpr size_t OFF_EXQ = OFF_W + SZ_W;
static constexpr size_t OFF_EXK = OFF_EXQ + SZ_ACT;
static constexpr size_t OFF_H1  = OFF_EXK + SZ_ACT;         // x3 branches
static constexpr size_t OFF_GR  = OFF_H1 + 3*SZ_ACT;        // x3 branches
static constexpr size_t OFF_TOK = OFF_GR + 3*SZ_ACT;        // 3 x (B,512,1024) bf16 flat

// ---------------- weight fp32 -> bf16 (flat row-major) ----------------
__global__ void k_prep(const float* __restrict__ w1q, const float* __restrict__ w2q, const float* __restrict__ wnq,
                       const float* __restrict__ w1k, const float* __restrict__ w2k, const float* __restrict__ wnk,
                       const float* __restrict__ w1v, const float* __restrict__ w2v, const float* __restrict__ wnv,
                       short* __restrict__ dst)
{
  const float* s1[3] = {w1q, w1k, w1v};
  const float* s2[3] = {w2q, w2k, w2v};
  const float* s3[3] = {wnq, wnk, wnv};
  const int stride = gridDim.x * blockDim.x;
  for (int i = blockIdx.x * blockDim.x + threadIdx.x; i < 983040; i += stride){
    int br = i / 327680;
    int r  = i - br * 327680;
    float v;
    if (r < 65536)        v = s1[br][r];
    else if (r < 196608)  v = s2[br][r - 65536];
    else                  v = s3[br][r - 196608];
    dst[i] = f2bf(v);
  }
}

// ------------- elu + transpose to token-major bf16 (verified in R1-R2) -------------
__global__ void k_elutr(const float* __restrict__ qin, const float* __restrict__ kin,
                        short* __restrict__ exq, short* __restrict__ exk)
{
  const int z = blockIdx.z;
  const int which = z >> 3, b = z & 7;
  const float* x = which ? kin : qin;
  short* dst = which ? exk : exq;
  const int c0 = blockIdx.y * 64, s0 = blockIdx.x * 64;
  __shared__ short t[64][65];
  const int tid = threadIdx.x;
  for (int i = tid; i < 64*64; i += 256){
    int c = i >> 6, s = i & 63;
    float v = x[((size_t)b*256 + c0 + c)*1024 + s0 + s];
    t[s][c] = f2bf(eluf(v));
  }
  __syncthreads();
  for (int i = tid; i < 64*64; i += 256){
    int s = i >> 6, c = i & 63;
    dst[((size_t)(b*1024 + s0 + s))*256 + c0 + c] = t[s][c];
  }
}

// ---------------- GEMM kernels: one 64Mx64N tile per WAVE, no LDS, no barriers ----
// Per ks-step: 8 coalesced 16B loads (4 A-frags + 4 B-frags) -> 16 MFMA (~310
// SIMD-cyc, covers next iteration's L2 latency). All operands stream from L2.
// XCD partition: bid&7 = XCD owns tokens [xcd*1024, xcd*1024+1024) (= batch xcd),
// so each XCD's B-slice + W (~3.5 MB) stays resident in its private 4 MB L2.
// Fragment layouts (verified rounds 1-9): A row=li k=hi*8+j; B col(token)=li,
// k=hi*8+j; C/D col=li row=hi*4+r.

// GEMM1: h1 = elu(W1 @ ex + b1) -> token-major bf16. grid 384 x 256thr.
__global__ __launch_bounds__(256, 1)
void k_g1(const short* __restrict__ wsW, const short* __restrict__ exq, const short* __restrict__ exk,
          const float* __restrict__ b1q, const float* __restrict__ b1k, const float* __restrict__ b1v,
          short* __restrict__ h1)
{
  const int tid = threadIdx.x, w = tid >> 6, hi = (tid >> 4) & 3, li = tid & 15;
  const int bid = blockIdx.x;
  const int xcd = bid & 7;
  const int wx = (bid >> 3) * 4 + w;        // 0..191
  const int nl = wx & 15, mzi = wx >> 4;    // nl 0..15, mzi 0..11
  const int m0 = (mzi & 3) << 6, z = mzi >> 2;
  const int n0 = xcd * 1024 + nl * 64;
  const short* act = (z == 0) ? exq : exk;
  const float* bias = (z == 0) ? b1q : ((z == 1) ? b1k : b1v);
  const short* W = wsW + (size_t)z * 327680;
  short* out = h1 + (size_t)z * NPIX * 256;

  f32x4 acc[4][4] = {};
  #pragma unroll 1
  for (int ks = 0; ks < 8; ks++){
    bf16x8 A[4], Bf[4];
    #pragma unroll
    for (int mt = 0; mt < 4; mt++)
      A[mt] = *(const bf16x8*)(W + (size_t)(m0 + mt*16 + li)*256 + ks*32 + hi*8);
    #pragma unroll
    for (int nt = 0; nt < 4; nt++)
      Bf[nt] = *(const bf16x8*)(act + (size_t)(n0 + nt*16 + li)*256 + ks*32 + hi*8);
    #pragma unroll
    for (int mt = 0; mt < 4; mt++)
      #pragma unroll
      for (int nt = 0; nt < 4; nt++)
        acc[mt][nt] = __builtin_amdgcn_mfma_f32_16x16x32_bf16(A[mt], Bf[nt], acc[mt][nt], 0, 0, 0);
  }
  #pragma unroll
  for (int mt = 0; mt < 4; mt++){
    const f32x4 bs = *(const f32x4*)(bias + m0 + mt*16 + hi*4);
    #pragma unroll
    for (int nt = 0; nt < 4; nt++){
      bf16x4 pk;
      #pragma unroll
      for (int r = 0; r < 4; r++)
        pk[r] = f2bf(eluf(acc[mt][nt][r] + bs[r]));
      *(bf16x4*)(out + (size_t)(n0 + nt*16 + li)*256 + m0 + mt*16 + hi*4) = pk;
    }
  }
}

// GEMM2: [a;g] = W2 @ h1 + b2 ; gr = x + a*sigmoid(g) -> token-major bf16.
// Wave covers 32 a-rows (m0..m0+31) AND the matching 32 g-rows (256+m0..).
// grid 768 x 256thr.
__global__ __launch_bounds__(256, 1)
void k_g2(const short* __restrict__ wsW, const short* __restrict__ h1,
          const float* __restrict__ b2q, const float* __restrict__ b2k, const float* __restrict__ b2v,
          const float* __restrict__ query, const float* __restrict__ key,
          short* __restrict__ gr)
{
  const int tid = threadIdx.x, w = tid >> 6, hi = (tid >> 4) & 3, li = tid & 15;
  const int bid = blockIdx.x;
  const int xcd = bid & 7;
  const int wx = (bid >> 3) * 4 + w;        // 0..383
  const int nl = wx & 15, mzi = wx >> 4;    // mzi 0..23
  const int m0 = (mzi & 7) << 5, z = mzi >> 3;
  const int n0 = xcd * 1024 + nl * 64;
  const short* act = h1 + (size_t)z * NPIX * 256;
  const float* bias = (z == 0) ? b2q : ((z == 1) ? b2k : b2v);
  const float* xin = (z == 0) ? query : key;
  const short* W = wsW + (size_t)z * 327680 + 65536;
  short* out = gr + (size_t)z * NPIX * 256;

  f32x4 aa[2][4] = {}, gg[2][4] = {};
  #pragma unroll 1
  for (int ks = 0; ks < 8; ks++){
    bf16x8 Aa[2], Ag[2], Bf[4];
    #pragma unroll
    for (int mt = 0; mt < 2; mt++){
      Aa[mt] = *(const bf16x8*)(W + (size_t)(m0 + mt*16 + li)*256 + ks*32 + hi*8);
      Ag[mt] = *(const bf16x8*)(W + (size_t)(256 + m0 + mt*16 + li)*256 + ks*32 + hi*8);
    }
    #pragma unroll
    for (int nt = 0; nt < 4; nt++)
      Bf[nt] = *(const bf16x8*)(act + (size_t)(n0 + nt*16 + li)*256 + ks*32 + hi*8);
    #pragma unroll
    for (int mt = 0; mt < 2; mt++)
      #pragma unroll
      for (int nt = 0; nt < 4; nt++){
        aa[mt][nt] = __builtin_amdgcn_mfma_f32_16x16x32_bf16(Aa[mt], Bf[nt], aa[mt][nt], 0, 0, 0);
        gg[mt][nt] = __builtin_amdgcn_mfma_f32_16x16x32_bf16(Ag[mt], Bf[nt], gg[mt][nt], 0, 0, 0);
      }
  }
  const int b = xcd, spb = n0 & 1023;
  #pragma unroll
  for (int mt = 0; mt < 2; mt++){
    const f32x4 ba = *(const f32x4*)(bias + m0 + mt*16 + hi*4);
    const f32x4 bg = *(const f32x4*)(bias + 256 + m0 + mt*16 + hi*4);
    #pragma unroll
    for (int nt = 0; nt < 4; nt++){
      bf16x4 pk;
      #pragma unroll
      for (int r = 0; r < 4; r++){
        float a  = aa[mt][nt][r] + ba[r];
        float g_ = gg[mt][nt][r] + bg[r];
        float xv = xin[(size_t)(b*256 + m0 + mt*16 + hi*4 + r)*1024 + spb + nt*16 + li];
        pk[r] = f2bf(xv + a * sigm(g_));
      }
      *(bf16x4*)(out + (size_t)(n0 + nt*16 + li)*256 + m0 + mt*16 + hi*4) = pk;
    }
  }
}

// GEMM3: tok = Wn @ gr + bn -> channel-major (B,512,1024) bf16. grid 768 x 256thr.
__global__ __launch_bounds__(256, 1)
void k_g3(const short* __restrict__ wsW, const short* __restrict__ gr,
          const float* __restrict__ bnq, const float* __restrict__ bnk, const float* __restrict__ bnv,
          short* __restrict__ tok)
{
  const int tid = threadIdx.x, w = tid >> 6, hi = (tid >> 4) & 3, li = tid & 15;
  const int bid = blockIdx.x;
  const int xcd = bid & 7;
  const int wx = (bid >> 3) * 4 + w;        // 0..383
  const int nl = wx & 15, mzi = wx >> 4;    // mzi 0..23
  const int m0 = (mzi & 7) << 6, z = mzi >> 3;
  const int n0 = xcd * 1024 + nl * 64;
  const short* act = gr + (size_t)z * NPIX * 256;
  const float* bias = (z == 0) ? bnq : ((z == 1) ? bnk : bnv);
  const short* W = wsW + (size_t)z * 327680 + 196608;
  short* tokz = tok + (size_t)z * NPIX * 512;

  f32x4 acc[4][4] = {};
  #pragma unroll 1
  for (int ks = 0; ks < 8; ks++){
    bf16x8 A[4], Bf[4];
    #pragma unroll
    for (int mt = 0; mt < 4; mt++)
      A[mt] = *(const bf16x8*)(W + (size_t)(m0 + mt*16 + li)*256 + ks*32 + hi*8);
    #pragma unroll
    for (int nt = 0; nt < 4; nt++)
      Bf[nt] = *(const bf16x8*)(act + (size_t)(n0 + nt*16 + li)*256 + ks*32 + hi*8);
    #pragma unroll
    for (int mt = 0; mt < 4; mt++)
      #pragma unroll
      for (int nt = 0; nt < 4; nt++)
        acc[mt][nt] = __builtin_amdgcn_mfma_f32_16x16x32_bf16(A[mt], Bf[nt], acc[mt][nt], 0, 0, 0);
  }
  const int b = xcd, spb = n0 & 1023;
  #pragma unroll
  for (int mt = 0; mt < 4; mt++){
    const f32x4 bs = *(const f32x4*)(bias + m0 + mt*16 + hi*4);
    #pragma unroll
    for (int nt = 0; nt < 4; nt++)
      #pragma unroll
      for (int r = 0; r < 4; r++){
        int m = m0 + mt*16 + hi*4 + r;
        tokz[((size_t)b*512 + m)*1024 + spb + nt*16 + li] = f2bf(acc[mt][nt][r] + bs[r]);
      }
  }
}

// ---------------- flash attention (unchanged; load-balance perm verified R2) ----------
__global__ void k_attn(const short* __restrict__ tok, float* __restrict__ out)
{
  const short* qtok = tok;
  const short* ktok = tok + (size_t)NPIX * 512;
  const short* vtok = tok + (size_t)2 * NPIX * 512;
  const int flat = blockIdx.x;
  const int p = flat >> 6;
  const int g4 = p >> 2, r4 = p & 3;
  // perm = [15,14,13,12, 0,1,2,3, 11,10,9,8, 4,5,6,7]
  const int qt = (g4 == 0) ? (15 - r4) : (g4 == 1) ? r4 : (g4 == 2) ? (11 - r4) : (4 + r4);
  const int bh = flat & 63;
  const int b = bh >> 3, nh = bh & 7;
  const int tid = threadIdx.x, lane = tid & 63, w = tid >> 6, g = (tid >> 4) & 3, li = tid & 15;
  const int qrow = qt*64 + w*16 + li;       // this lane's query token
  __shared__ short Kl[64*64];
  __shared__ short Vt[64*64];               // V transposed: [d][k]
  __shared__ short Pl[4][1024];             // per-wave P [16 q][64 k]

  const short* qptr = qtok + ((size_t)(b*1024 + qrow))*512 + nh*64;
  bf16x8 qf0 = *(const bf16x8*)(qptr + g*8);
  bf16x8 qf1 = *(const bf16x8*)(qptr + 32 + g*8);

  f32x4 accO[4] = {};                       // O^T: 4 d-frags x (16d x 16q)
  float mrun = -1e30f, lrun = 0.f;
  const float scale = 0.04419417382415922f; // 1/sqrt(512)
  short* Pw = &Pl[w][0];

  for (int kt = 0; kt <= qt; kt++){
    const int kb = kt * 64;
    __syncthreads();
    #pragma unroll
    for (int it = 0; it < 2; it++){
      int i = tid + it*256;
      int kr = i >> 3, kc = i & 7;
      bf16x8 v = *(const bf16x8*)(ktok + ((size_t)(b*1024 + kb + kr))*512 + nh*64 + kc*8);
      *(bf16x8*)(Kl + ((kr*64 + kc*8) ^ ((kr & 7) << 3))) = v;
    }
    #pragma unroll
    for (int it = 0; it < 2; it++){
      int d0 = w*8 + it*32;                 // d uniform within wave -> conflict-free writes
      bf16x8 v = *(const bf16x8*)(vtok + ((size_t)(b*1024 + kb + lane))*512 + nh*64 + d0);
      #pragma unroll
      for (int j = 0; j < 8; j++){
        int d = d0 + j;
        Vt[(d*64 + lane) ^ ((d & 7) << 3)] = v[j];
      }
    }
    __syncthreads();

    // S^T frags: 4 x (16 keys x 16 q)
    float pv[16];
    float mt_ = -1e30f;
    const bool diag = (kt == qt);
    #pragma unroll
    for (int kf = 0; kf < 4; kf++){
      f32x4 sa = {};
      const int krow = kf*16 + li;
      bf16x8 ka  = *(const bf16x8*)(Kl + ((krow*64 + g*8) ^ ((krow & 7) << 3)));
      bf16x8 kbf = *(const bf16x8*)(Kl + ((krow*64 + 32 + g*8) ^ ((krow & 7) << 3)));
      sa = __builtin_amdgcn_mfma_f32_16x16x32_bf16(ka, qf0, sa, 0, 0, 0);
      sa = __builtin_amdgcn_mfma_f32_16x16x32_bf16(kbf, qf1, sa, 0, 0, 0);
      #pragma unroll
      for (int r = 0; r < 4; r++){
        const int keyg = kb + kf*16 + g*4 + r;
        float s = sa[r] * scale;
        const bool ok = (!diag) || (keyg < qrow);   // strict causal
        s = ok ? s : -1e30f;
        pv[kf*4 + r] = s;
        mt_ = fmaxf(mt_, s);
      }
    }
    mt_ = fmaxf(mt_, __shfl_xor(mt_, 16));
    mt_ = fmaxf(mt_, __shfl_xor(mt_, 32));
    const float mnew = fmaxf(mrun, mt_);
    const float alpha = __expf(mrun - mnew);
    short pr[16];
    float rs = 0.f;
    #pragma unroll
    for (int i2 = 0; i2 < 16; i2++){
      float p2 = (pv[i2] > -9e29f) ? __expf(pv[i2] - mnew) : 0.f;
      short pb = f2bf(p2);
      pr[i2] = pb;
      rs += bf2f(pb);            // denominator from rounded P (consistent with numerator)
    }
    rs += __shfl_xor(rs, 16);
    rs += __shfl_xor(rs, 32);
    lrun = lrun * alpha + rs;
    mrun = mnew;
    #pragma unroll
    for (int df = 0; df < 4; df++){
      accO[df][0] *= alpha; accO[df][1] *= alpha;
      accO[df][2] *= alpha; accO[df][3] *= alpha;
    }
    // P rows to per-wave LDS (b32 packed pairs; keys 4g+2rp consecutive)
    #pragma unroll
    for (int kf = 0; kf < 4; kf++){
      #pragma unroll
      for (int rp = 0; rp < 2; rp++){
        bf16x2 two;
        two[0] = pr[kf*4 + rp*2];
        two[1] = pr[kf*4 + rp*2 + 1];
        const int key = kf*16 + g*4 + rp*2;
        *(bf16x2*)(Pw + ((li*64 + key) ^ ((li & 7) << 3))) = two;
      }
    }
    // O^T += V^T @ P^T
    #pragma unroll
    for (int kc = 0; kc < 2; kc++){
      bf16x8 pf = *(const bf16x8*)(Pw + ((li*64 + kc*32 + g*8) ^ ((li & 7) << 3)));
      #pragma unroll
      for (int df = 0; df < 4; df++){
        const int dr = df*16 + li;
        bf16x8 vf = *(const bf16x8*)(Vt + ((dr*64 + kc*32 + g*8) ^ ((dr & 7) << 3)));
        accO[df] = __builtin_amdgcn_mfma_f32_16x16x32_bf16(vf, pf, accO[df], 0, 0, 0);
      }
    }
  }
  const float inv = (lrun > 0.f) ? (1.f / lrun) : 0.f;  // row 0: lrun==0 -> zeros (start_mask)
  #pragma unroll
  for (int df = 0; df < 4; df++){
    #pragma unroll
    for (int r = 0; r < 4; r++){
      const int d = df*16 + g*4 + r;
      out[((size_t)b*512 + nh*64 + d)*1024 + qrow] = accO[df][r] * inv;
    }
  }
}

extern "C" void kernel_launch(void* const* d_in, const int* in_sizes, int n_in,
                              void* d_out, int out_size, void* d_ws, size_t ws_size,
                              hipStream_t stream)
{
  (void)in_sizes; (void)n_in; (void)out_size; (void)ws_size;
  const float* query = (const float*)d_in[0];
  const float* key   = (const float*)d_in[1];
  const float* w1[3] = {(const float*)d_in[2],  (const float*)d_in[8],  (const float*)d_in[14]};
  const float* b1[3] = {(const float*)d_in[3],  (const float*)d_in[9],  (const float*)d_in[15]};
  const float* w2[3] = {(const float*)d_in[4],  (const float*)d_in[10], (const float*)d_in[16]};
  const float* b2[3] = {(const float*)d_in[5],  (const float*)d_in[11], (const float*)d_in[17]};
  const float* wn[3] = {(const float*)d_in[6],  (const float*)d_in[12], (const float*)d_in[18]};
  const float* bn[3] = {(const float*)d_in[7],  (const float*)d_in[13], (const float*)d_in[19]};

  char* ws = (char*)d_ws;
  short* wsW = (short*)(ws + OFF_W);
  short* exq = (short*)(ws + OFF_EXQ);
  short* exk = (short*)(ws + OFF_EXK);
  short* h1  = (short*)(ws + OFF_H1);
  short* gr  = (short*)(ws + OFF_GR);
  short* tok = (short*)(ws + OFF_TOK);
  float* out = (float*)d_out;

  k_prep<<<dim3(960), dim3(256), 0, stream>>>(w1[0], w2[0], wn[0],
                                              w1[1], w2[1], wn[1],
                                              w1[2], w2[2], wn[2], wsW);
  k_elutr<<<dim3(16, 4, 16), dim3(256), 0, stream>>>(query, key, exq, exk);
  k_g1<<<dim3(384), dim3(256), 0, stream>>>(wsW, exq, exk, b1[0], b1[1], b1[2], h1);
  k_g2<<<dim3(768), dim3(256), 0, stream>>>(wsW, h1, b2[0], b2[1], b2[2], query, key, gr);
  k_g3<<<dim3(768), dim3(256), 0, stream>>>(wsW, gr, bn[0], bn[1], bn[2], tok);
  k_attn<<<dim3(1024), dim3(256), 0, stream>>>(tok, out);
}

// Round 11
// 90.674 us; speedup vs baseline: 1.3790x; 1.3790x over previous
//
#include <hip/hip_runtime.h>
#include <cstdint>
#include <cstddef>

typedef __attribute__((ext_vector_type(4))) float f32x4;
typedef __attribute__((ext_vector_type(8))) short bf16x8;
typedef __attribute__((ext_vector_type(4))) short bf16x4;
typedef __attribute__((ext_vector_type(2))) short bf16x2;

#define DEVI static __device__ __forceinline__

DEVI short f2bf(float f){
  union { float f; uint32_t u; } v; v.f = f;
  uint32_t r = v.u + 0x7FFFu + ((v.u >> 16) & 1u);
  return (short)(r >> 16);
}
DEVI float bf2f(short h){
  union { uint32_t u; float f; } v; v.u = ((uint32_t)(uint16_t)h) << 16;
  return v.f;
}
DEVI float eluf(float x){ return x > 0.f ? x : (__expf(x) - 1.f); }
DEVI float sigm(float x){ return 1.f / (1.f + __expf(-x)); }

DEVI void gload16(const void* g, void* l){
  __builtin_amdgcn_global_load_lds((const __attribute__((address_space(1))) void*)g,
                                   (__attribute__((address_space(3))) void*)l, 16, 0, 0);
}

static constexpr int NPIX = 8 * 1024;   // B*S pixels

// ---- workspace layout (bytes) ----
static constexpr size_t SZ_W   = (size_t)983040 * 2;        // 3 branches x 20 stages x 64 rows x 32 slots x 8 shorts
static constexpr size_t SZ_ACT = (size_t)NPIX * 256 * 2;
static constexpr size_t OFF_W   = 0;
static constexpr size_t OFF_TOK = OFF_W + SZ_W + 8*SZ_ACT;  // 3 x (B,512,1024) bf16 flat

// ---------------- weight prep: fp32 -> bf16, stage-major, ROTATION-swizzled --------
// Per branch z: 20 stages of 64 rows x 256 k (32 KB each).
// Stage map: s 0-3  = W1 rows s*64
//            s 4-11 = W2, t=s-4: even t -> a-rows (t>>1)*64, odd t -> g-rows 256+(t>>1)*64
//            s 12-19= Wn rows (s-12)*64
// Within a stage, row r (0..63) stores logical k-slot k0 (16B unit, k=k0*8..k0*8+7)
// at PHYSICAL slot p = (k0 + r) & 31  -> on ds_read, lanes 0..7 hit 8 distinct
// bank-quads (the measured 8-way conflict in R7's XOR layout becomes <=2-way).
// k_branch gloads stages linearly and reads with the same rotation.
__global__ void k_prep(const float* __restrict__ w1q, const float* __restrict__ w2q, const float* __restrict__ wnq,
                       const float* __restrict__ w1k, const float* __restrict__ w2k, const float* __restrict__ wnk,
                       const float* __restrict__ w1v, const float* __restrict__ w2v, const float* __restrict__ wnv,
                       short* __restrict__ dst)
{
  const float* s1[3] = {w1q, w1k, w1v};
  const float* s2[3] = {w2q, w2k, w2v};
  const float* s3[3] = {wnq, wnk, wnv};
  int u = blockIdx.x * 256 + threadIdx.x;      // one 16B unit per thread
  if (u >= 122880) return;                     // 3 * 20 * 64 * 32
  int z = u / 40960, rem = u % 40960;
  int s = rem >> 11, r = (rem >> 5) & 63, p = rem & 31;
  int k0 = (p - r) & 31;                       // logical slot stored at physical p
  const float* src; int row;
  if (s < 4)      { src = s1[z]; row = s*64 + r; }
  else if (s < 12){ int t = s - 4; src = s2[z]; row = ((t & 1) ? 256 : 0) + (t >> 1)*64 + r; }
  else            { src = s3[z]; row = (s - 12)*64 + r; }
  const float* pp = src + (size_t)row*256 + k0*8;
  short* dq = dst + (size_t)u*8;
  #pragma unroll
  for (int e = 0; e < 8; e++) dq[e] = f2bf(pp[e]);
}

// ---------------- fused branch kernel, v9 ----------------
// One block = 32 tokens x one branch z; 4 waves, 256 thr. M is split across
// waves: stage = 64 W-rows, wave w owns rows w*16..w*16+15 (one A-frag/ks).
// Each A ds_read_b128 feeds nt=2 MFMA (32 tokens/wave) -> read:MFMA = 0.5.
// W streams via global_load_lds (pre-rotated, linear dest), double-buffered,
// 20 stages, ONE barrier per stage. h1/gr: block-shared 16 KB LDS (rotation-
// swizzled), hoisted to registers (bH/bG) right after their producing phase.
// LDS = 64 KB (W dbuf) + 16 KB = 80 KB -> exactly 2 blocks/CU. Grid 768.
__global__ __launch_bounds__(256, 2)
void k_branch(const short* __restrict__ wsW,
              const float* __restrict__ query, const float* __restrict__ key,
              const float* __restrict__ b1q, const float* __restrict__ b1k, const float* __restrict__ b1v,
              const float* __restrict__ b2q, const float* __restrict__ b2k, const float* __restrict__ b2v,
              const float* __restrict__ bnq, const float* __restrict__ bnk, const float* __restrict__ bnv,
              short* __restrict__ tok)
{
  __shared__ short sW[2][16384];   // 2 x (64 rows x 256 k) = 2 x 32 KB
  __shared__ short sHG[32*256];    // h1 then gr: 32 tokens x 256 (16 KB)

  const int z = blockIdx.y;
  const float* xin = (z == 0) ? query : key;
  const float* b1z = (z == 0) ? b1q : ((z == 1) ? b1k : b1v);
  const float* b2z = (z == 0) ? b2q : ((z == 1) ? b2k : b2v);
  const float* bnz = (z == 0) ? bnq : ((z == 1) ? bnk : bnv);
  const short* Wz = wsW + (size_t)z * 327680;
  short* tokz = tok + (size_t)z * NPIX * 512;

  const int tid = threadIdx.x, w = tid >> 6, g = (tid >> 4) & 3, li = tid & 15;
  const int tile = blockIdx.x;
  const int b = tile >> 5, sp0 = (tile & 31) * 32;
  const int rl = w*16 + li;                       // this lane's stage row
  const float* xb = xin + (size_t)b * 256 * 1024;

  // stage s -> buffer nb: pure linear copy (8 x 16B per thread)
#define STAGE(S, NB)                                                              \
  { const char* gs_ = (const char*)Wz + (size_t)(S)*32768 + tid*16;               \
    char* ls_ = (char*)&sW[(NB)][0] + w*1024;                                     \
    _Pragma("unroll")                                                             \
    for (int i_ = 0; i_ < 8; i_++) gload16(gs_ + i_*4096, ls_ + i_*4096); }

  STAGE(0, 0);

  // GEMM1 B-fragments: elu(x), transpose-free from global.
  // bB[nt][ks][j] = elu(x)[k=ks*32+g*8+j][token sp0 + nt*16 + li]
  bf16x8 bB[2][8];
  #pragma unroll
  for (int nt = 0; nt < 2; nt++)
    #pragma unroll
    for (int ks = 0; ks < 8; ks++)
      #pragma unroll
      for (int j = 0; j < 8; j++){
        float e = xb[(size_t)(ks*32 + g*8 + j)*1024 + sp0 + nt*16 + li];
        bB[nt][ks][j] = f2bf(eluf(e));
      }
  __syncthreads();   // stage 0 resident

  // ---- GEMM1: h1 = elu(W1 @ ex + b1) -> sHG (4 stages) ----
  for (int s = 0; s < 4; s++){
    STAGE(s + 1, (s + 1) & 1);
    const short* buf = &sW[s & 1][0];
    f32x4 acc[2] = {};
    #pragma unroll
    for (int ks = 0; ks < 8; ks++){
      const int p = ((ks*4 + g) + rl) & 31;
      bf16x8 afr = *(const bf16x8*)(buf + rl*256 + p*8);
      #pragma unroll
      for (int nt = 0; nt < 2; nt++)
        acc[nt] = __builtin_amdgcn_mfma_f32_16x16x32_bf16(afr, bB[nt][ks], acc[nt], 0, 0, 0);
    }
    const int mb = s*64 + w*16 + g*4;
    const f32x4 bias = *(const f32x4*)(b1z + mb);
    #pragma unroll
    for (int nt = 0; nt < 2; nt++){
      const int tokl = nt*16 + li;
      bf16x4 pk;
      #pragma unroll
      for (int r = 0; r < 4; r++)
        pk[r] = f2bf(eluf(acc[nt][r] + bias[r]));
      const int slot = ((mb >> 3) + tokl) & 31;
      *(bf16x4*)(sHG + tokl*256 + slot*8 + (g & 1)*4) = pk;
    }
    __syncthreads();
  }

  // hoist h1 into registers (all waves; sHG free for gr afterwards)
  bf16x8 bH[2][8];
  #pragma unroll
  for (int nt = 0; nt < 2; nt++){
    const int tokl = nt*16 + li;
    #pragma unroll
    for (int ks = 0; ks < 8; ks++){
      const int p = ((ks*4 + g) + tokl) & 31;
      bH[nt][ks] = *(const bf16x8*)(sHG + tokl*256 + p*8);
    }
  }

  // ---- GEMM2: [a;g] = W2 @ h1 + b2 ; gr = x + a*sig(g) -> sHG (8 stages) ----
  f32x4 aa[2];
  for (int s = 4; s < 12; s++){
    const int t = s - 4;
    STAGE(s + 1, (s + 1) & 1);
    const short* buf = &sW[s & 1][0];
    f32x4 acc[2] = {};
    #pragma unroll
    for (int ks = 0; ks < 8; ks++){
      const int p = ((ks*4 + g) + rl) & 31;
      bf16x8 afr = *(const bf16x8*)(buf + rl*256 + p*8);
      #pragma unroll
      for (int nt = 0; nt < 2; nt++)
        acc[nt] = __builtin_amdgcn_mfma_f32_16x16x32_bf16(afr, bH[nt][ks], acc[nt], 0, 0, 0);
    }
    if ((t & 1) == 0){
      aa[0] = acc[0]; aa[1] = acc[1];           // a-half, hold across one stage
    } else {
      const int mb = (t >> 1)*64 + w*16 + g*4;  // epilogue: a from aa, g from acc
      const f32x4 ba = *(const f32x4*)(b2z + mb);
      const f32x4 bg = *(const f32x4*)(b2z + 256 + mb);
      #pragma unroll
      for (int nt = 0; nt < 2; nt++){
        const int tokl = nt*16 + li;
        bf16x4 pk;
        #pragma unroll
        for (int r = 0; r < 4; r++){
          float a  = aa[nt][r] + ba[r];
          float g_ = acc[nt][r] + bg[r];
          float xv = xb[(size_t)(mb + r)*1024 + sp0 + tokl];
          pk[r] = f2bf(xv + a * sigm(g_));
        }
        const int slot = ((mb >> 3) + tokl) & 31;
        *(bf16x4*)(sHG + tokl*256 + slot*8 + (g & 1)*4) = pk;
      }
    }
    __syncthreads();
  }

  // hoist gr into registers
  bf16x8 bG[2][8];
  #pragma unroll
  for (int nt = 0; nt < 2; nt++){
    const int tokl = nt*16 + li;
    #pragma unroll
    for (int ks = 0; ks < 8; ks++){
      const int p = ((ks*4 + g) + tokl) & 31;
      bG[nt][ks] = *(const bf16x8*)(sHG + tokl*256 + p*8);
    }
  }

  // ---- GEMM3: tok = Wn @ gr + bn -> global (B,512,1024) bf16 (8 stages) ----
  for (int s = 12; s < 20; s++){
    if (s < 19) STAGE(s + 1, (s + 1) & 1);
    const short* buf = &sW[s & 1][0];
    f32x4 acc[2] = {};
    #pragma unroll
    for (int ks = 0; ks < 8; ks++){
      const int p = ((ks*4 + g) + rl) & 31;
      bf16x8 afr = *(const bf16x8*)(buf + rl*256 + p*8);
      #pragma unroll
      for (int nt = 0; nt < 2; nt++)
        acc[nt] = __builtin_amdgcn_mfma_f32_16x16x32_bf16(afr, bG[nt][ks], acc[nt], 0, 0, 0);
    }
    const int mb = (s - 12)*64 + w*16 + g*4;
    const f32x4 bias = *(const f32x4*)(bnz + mb);
    #pragma unroll
    for (int nt = 0; nt < 2; nt++)
      #pragma unroll
      for (int r = 0; r < 4; r++)
        tokz[((size_t)b*512 + mb + r)*1024 + sp0 + nt*16 + li] = f2bf(acc[nt][r] + bias[r]);
    if (s < 19) __syncthreads();
  }
#undef STAGE
}

// ---------------- flash attention (unchanged; verified + load-balance perm) --------
__global__ void k_attn(const short* __restrict__ tok, float* __restrict__ out)
{
  const short* qtok = tok;
  const short* ktok = tok + (size_t)NPIX * 512;
  const short* vtok = tok + (size_t)2 * NPIX * 512;
  const int flat = blockIdx.x;
  const int p = flat >> 6;
  const int g4 = p >> 2, r4 = p & 3;
  // perm = [15,14,13,12, 0,1,2,3, 11,10,9,8, 4,5,6,7]
  const int qt = (g4 == 0) ? (15 - r4) : (g4 == 1) ? r4 : (g4 == 2) ? (11 - r4) : (4 + r4);
  const int bh = flat & 63;
  const int b = bh >> 3, nh = bh & 7;
  const int tid = threadIdx.x, lane = tid & 63, w = tid >> 6, g = (tid >> 4) & 3, li = tid & 15;
  const int qrow = qt*64 + w*16 + li;       // this lane's query token
  __shared__ short Kl[64*64];
  __shared__ short Vt[64*64];               // V transposed: [d][k]
  __shared__ short Pl[4][1024];             // per-wave P [16 q][64 k]

  const short* qptr = qtok + ((size_t)(b*1024 + qrow))*512 + nh*64;
  bf16x8 qf0 = *(const bf16x8*)(qptr + g*8);
  bf16x8 qf1 = *(const bf16x8*)(qptr + 32 + g*8);

  f32x4 accO[4] = {};                       // O^T: 4 d-frags x (16d x 16q)
  float mrun = -1e30f, lrun = 0.f;
  const float scale = 0.04419417382415922f; // 1/sqrt(512)
  short* Pw = &Pl[w][0];

  for (int kt = 0; kt <= qt; kt++){
    const int kb = kt * 64;
    __syncthreads();
    #pragma unroll
    for (int it = 0; it < 2; it++){
      int i = tid + it*256;
      int kr = i >> 3, kc = i & 7;
      bf16x8 v = *(const bf16x8*)(ktok + ((size_t)(b*1024 + kb + kr))*512 + nh*64 + kc*8);
      *(bf16x8*)(Kl + ((kr*64 + kc*8) ^ ((kr & 7) << 3))) = v;
    }
    #pragma unroll
    for (int it = 0; it < 2; it++){
      int d0 = w*8 + it*32;                 // d uniform within wave -> conflict-free writes
      bf16x8 v = *(const bf16x8*)(vtok + ((size_t)(b*1024 + kb + lane))*512 + nh*64 + d0);
      #pragma unroll
      for (int j = 0; j < 8; j++){
        int d = d0 + j;
        Vt[(d*64 + lane) ^ ((d & 7) << 3)] = v[j];
      }
    }
    __syncthreads();

    // S^T frags: 4 x (16 keys x 16 q)
    float pv[16];
    float mt_ = -1e30f;
    const bool diag = (kt == qt);
    #pragma unroll
    for (int kf = 0; kf < 4; kf++){
      f32x4 sa = {};
      const int krow = kf*16 + li;
      bf16x8 ka  = *(const bf16x8*)(Kl + ((krow*64 + g*8) ^ ((krow & 7) << 3)));
      bf16x8 kbf = *(const bf16x8*)(Kl + ((krow*64 + 32 + g*8) ^ ((krow & 7) << 3)));
      sa = __builtin_amdgcn_mfma_f32_16x16x32_bf16(ka, qf0, sa, 0, 0, 0);
      sa = __builtin_amdgcn_mfma_f32_16x16x32_bf16(kbf, qf1, sa, 0, 0, 0);
      #pragma unroll
      for (int r = 0; r < 4; r++){
        const int keyg = kb + kf*16 + g*4 + r;
        float s = sa[r] * scale;
        const bool ok = (!diag) || (keyg < qrow);   // strict causal
        s = ok ? s : -1e30f;
        pv[kf*4 + r] = s;
        mt_ = fmaxf(mt_, s);
      }
    }
    mt_ = fmaxf(mt_, __shfl_xor(mt_, 16));
    mt_ = fmaxf(mt_, __shfl_xor(mt_, 32));
    const float mnew = fmaxf(mrun, mt_);
    const float alpha = __expf(mrun - mnew);
    short pr[16];
    float rs = 0.f;
    #pragma unroll
    for (int i2 = 0; i2 < 16; i2++){
      float p2 = (pv[i2] > -9e29f) ? __expf(pv[i2] - mnew) : 0.f;
      short pb = f2bf(p2);
      pr[i2] = pb;
      rs += bf2f(pb);            // denominator from rounded P (consistent with numerator)
    }
    rs += __shfl_xor(rs, 16);
    rs += __shfl_xor(rs, 32);
    lrun = lrun * alpha + rs;
    mrun = mnew;
    #pragma unroll
    for (int df = 0; df < 4; df++){
      accO[df][0] *= alpha; accO[df][1] *= alpha;
      accO[df][2] *= alpha; accO[df][3] *= alpha;
    }
    // P rows to per-wave LDS (b32 packed pairs; keys 4g+2rp consecutive)
    #pragma unroll
    for (int kf = 0; kf < 4; kf++){
      #pragma unroll
      for (int rp = 0; rp < 2; rp++){
        bf16x2 two;
        two[0] = pr[kf*4 + rp*2];
        two[1] = pr[kf*4 + rp*2 + 1];
        const int key = kf*16 + g*4 + rp*2;
        *(bf16x2*)(Pw + ((li*64 + key) ^ ((li & 7) << 3))) = two;
      }
    }
    // O^T += V^T @ P^T
    #pragma unroll
    for (int kc = 0; kc < 2; kc++){
      bf16x8 pf = *(const bf16x8*)(Pw + ((li*64 + kc*32 + g*8) ^ ((li & 7) << 3)));
      #pragma unroll
      for (int df = 0; df < 4; df++){
        const int dr = df*16 + li;
        bf16x8 vf = *(const bf16x8*)(Vt + ((dr*64 + kc*32 + g*8) ^ ((dr & 7) << 3)));
        accO[df] = __builtin_amdgcn_mfma_f32_16x16x32_bf16(vf, pf, accO[df], 0, 0, 0);
      }
    }
  }
  const float inv = (lrun > 0.f) ? (1.f / lrun) : 0.f;  // row 0: lrun==0 -> zeros (start_mask)
  #pragma unroll
  for (int df = 0; df < 4; df++){
    #pragma unroll
    for (int r = 0; r < 4; r++){
      const int d = df*16 + g*4 + r;
      out[((size_t)b*512 + nh*64 + d)*1024 + qrow] = accO[df][r] * inv;
    }
  }
}

extern "C" void kernel_launch(void* const* d_in, const int* in_sizes, int n_in,
                              void* d_out, int out_size, void* d_ws, size_t ws_size,
                              hipStream_t stream)
{
  (void)in_sizes; (void)n_in; (void)out_size; (void)ws_size;
  const float* query = (const float*)d_in[0];
  const float* key   = (const float*)d_in[1];
  const float* w1[3] = {(const float*)d_in[2],  (const float*)d_in[8],  (const float*)d_in[14]};
  const float* b1[3] = {(const float*)d_in[3],  (const float*)d_in[9],  (const float*)d_in[15]};
  const float* w2[3] = {(const float*)d_in[4],  (const float*)d_in[10], (const float*)d_in[16]};
  const float* b2[3] = {(const float*)d_in[5],  (const float*)d_in[11], (const float*)d_in[17]};
  const float* wn[3] = {(const float*)d_in[6],  (const float*)d_in[12], (const float*)d_in[18]};
  const float* bn[3] = {(const float*)d_in[7],  (const float*)d_in[13], (const float*)d_in[19]};

  char* ws = (char*)d_ws;
  short* wsW = (short*)(ws + OFF_W);
  short* tok = (short*)(ws + OFF_TOK);
  float* out = (float*)d_out;

  k_prep<<<dim3(480), dim3(256), 0, stream>>>(w1[0], w2[0], wn[0],
                                              w1[1], w2[1], wn[1],
                                              w1[2], w2[2], wn[2], wsW);
  k_branch<<<dim3(256, 3), dim3(256), 0, stream>>>(wsW, query, key,
                                                   b1[0], b1[1], b1[2],
                                                   b2[0], b2[1], b2[2],
                                                   bn[0], bn[1], bn[2], tok);
  k_attn<<<dim3(1024), dim3(256), 0, stream>>>(tok, out);
}

// Round 12
// 86.155 us; speedup vs baseline: 1.4513x; 1.0525x over previous
//
#include <hip/hip_runtime.h>
#include <cstdint>
#include <cstddef>

typedef __attribute__((ext_vector_type(4))) float f32x4;
typedef __attribute__((ext_vector_type(8))) short bf16x8;
typedef __attribute__((ext_vector_type(4))) short bf16x4;
typedef __attribute__((ext_vector_type(2))) short bf16x2;

#define DEVI static __device__ __forceinline__

DEVI short f2bf(float f){
  union { float f; uint32_t u; } v; v.f = f;
  uint32_t r = v.u + 0x7FFFu + ((v.u >> 16) & 1u);
  return (short)(r >> 16);
}
DEVI float bf2f(short h){
  union { uint32_t u; float f; } v; v.u = ((uint32_t)(uint16_t)h) << 16;
  return v.f;
}
DEVI float eluf(float x){ return x > 0.f ? x : (__expf(x) - 1.f); }
DEVI float sigm(float x){ return 1.f / (1.f + __expf(-x)); }

static constexpr int NPIX = 8 * 1024;   // B*S pixels

// ---- workspace layout (bytes) ----
static constexpr size_t SZ_W   = (size_t)983040 * 2;        // 3 x (w1 64K + w2 128K + wn 128K shorts), row-major
static constexpr size_t SZ_ACT = (size_t)NPIX * 256 * 2;
static constexpr size_t OFF_W   = 0;
static constexpr size_t OFF_TOK = OFF_W + SZ_W + 8*SZ_ACT;  // 3 x (B,512,1024) bf16 flat

// ---------------- weight fp32 -> bf16 (flat row-major) ----------------
__global__ void k_prep(const float* __restrict__ w1q, const float* __restrict__ w2q, const float* __restrict__ wnq,
                       const float* __restrict__ w1k, const float* __restrict__ w2k, const float* __restrict__ wnk,
                       const float* __restrict__ w1v, const float* __restrict__ w2v, const float* __restrict__ wnv,
                       short* __restrict__ dst)
{
  const float* s1[3] = {w1q, w1k, w1v};
  const float* s2[3] = {w2q, w2k, w2v};
  const float* s3[3] = {wnq, wnk, wnv};
  const int stride = gridDim.x * blockDim.x;
  for (int i = blockIdx.x * blockDim.x + threadIdx.x; i < 983040; i += stride){
    int br = i / 327680;
    int r  = i - br * 327680;
    float v;
    if (r < 65536)        v = s1[br][r];
    else if (r < 196608)  v = s2[br][r - 65536];
    else                  v = s3[br][r - 196608];
    dst[i] = f2bf(v);
  }
}

// ---------------- fused branch kernel (best-known config, benched 49 us in R7) ------
// One block = 64 tokens x one branch z; 4 waves; wave owns 16 tokens end-to-end
// (B-operands in registers; h1/gr via WAVE-PRIVATE LDS, no activation barriers).
// W staged block-wide: reg-staged, double-buffered 32-row x 256-k LDS tiles,
// 40 stages, ONE barrier per stage; stage s+1's global loads issued before
// stage s's MFMA block. LDS = 2x16KB + 4x8KB = 64 KB -> 2 blocks/CU.
DEVI const short* stage_ptr(const short* W1z, int s, int& r0){
  if (s < 8){ r0 = s << 5; return W1z; }
  if (s < 24){ int t = s - 8; r0 = ((t & 2) << 7) + ((t >> 2) << 6) + ((t & 1) << 5); return W1z + 65536; }
  int t = s - 24; r0 = t << 5; return W1z + 196608;
}

__global__ __launch_bounds__(256, 2)
void k_branch(const short* __restrict__ wsW,
              const float* __restrict__ query, const float* __restrict__ key,
              const float* __restrict__ b1q, const float* __restrict__ b1k, const float* __restrict__ b1v,
              const float* __restrict__ b2q, const float* __restrict__ b2k, const float* __restrict__ b2v,
              const float* __restrict__ bnq, const float* __restrict__ bnk, const float* __restrict__ bnv,
              short* __restrict__ tok)
{
  __shared__ short sW[2][8192];    // 2 x (32 rows x 256 k), XOR-swizzled (16 KB each)
  __shared__ short sHG[4][4096];   // per-wave 16 tokens x 256 (h1, then gr overlay; 8 KB each)

  const int z = blockIdx.y;
  const float* xin = (z == 0) ? query : key;
  const float* b1z = (z == 0) ? b1q : ((z == 1) ? b1k : b1v);
  const float* b2z = (z == 0) ? b2q : ((z == 1) ? b2k : b2v);
  const float* bnz = (z == 0) ? bnq : ((z == 1) ? bnk : bnv);
  const short* W1 = wsW + (size_t)z * 327680;
  short* tokz = tok + (size_t)z * NPIX * 512;

  const int tid = threadIdx.x, w = tid >> 6, g = (tid >> 4) & 3, li = tid & 15;
  const int tile = blockIdx.x;
  const int b = tile >> 4, sp0 = (tile & 15) * 64;
  const int sb = sp0 + w*16;       // wave's 16-token base
  short* sHw = &sHG[w][0];
  const float* xb = xin + (size_t)b * 256 * 1024;

  bf16x8 stg[4];
#define STAGE_ISSUE(SN)                                                         \
  { int r0_; const short* Wb_ = stage_ptr(W1, (SN), r0_);                       \
    _Pragma("unroll")                                                           \
    for (int it = 0; it < 4; it++){                                             \
      int gi = tid + it*256;                                                    \
      stg[it] = *(const bf16x8*)(Wb_ + (size_t)(r0_ + (gi >> 5))*256 + ((gi & 31) << 3)); } }
#define STAGE_WRITE(BUF)                                                        \
  { _Pragma("unroll")                                                           \
    for (int it = 0; it < 4; it++){                                             \
      int gi = tid + it*256; int row = gi >> 5;                                 \
      *(bf16x8*)((BUF) + row*256 + ((((gi & 31) ^ (row & 7))) << 3)) = stg[it]; } }

  STAGE_ISSUE(0);

  bf16x8 bB[8];
  #pragma unroll
  for (int ks = 0; ks < 8; ks++)
    #pragma unroll
    for (int j = 0; j < 8; j++){
      float e = xb[(size_t)(ks*32 + g*8 + j)*1024 + sb + li];
      bB[ks][j] = f2bf(eluf(e));
    }
  STAGE_WRITE(sW[0]);
  __syncthreads();

  // ---- GEMM1: h1 = elu(W1 @ ex + b1) -> sHw[token][m] (8 stages) ----
  for (int s = 0; s < 8; s++){
    STAGE_ISSUE(s + 1);
    const short* bufc = &sW[s & 1][0];
    f32x4 acc[2] = {};
    #pragma unroll
    for (int ks = 0; ks < 8; ks++)
      #pragma unroll
      for (int mt = 0; mt < 2; mt++){
        bf16x8 afr = *(const bf16x8*)(bufc + (mt*16 + li)*256 + (((ks*4 + g) ^ (li & 7)) << 3));
        acc[mt] = __builtin_amdgcn_mfma_f32_16x16x32_bf16(afr, bB[ks], acc[mt], 0, 0, 0);
      }
    #pragma unroll
    for (int mt = 0; mt < 2; mt++){
      int m0 = s*32 + mt*16 + g*4;
      bf16x4 pk;
      #pragma unroll
      for (int r = 0; r < 4; r++)
        pk[r] = f2bf(eluf(acc[mt][r] + b1z[m0 + r]));
      *(bf16x4*)(sHw + li*256 + (m0 ^ ((li & 7) << 3))) = pk;
    }
    STAGE_WRITE(sW[(s + 1) & 1]);
    __syncthreads();
  }

  bf16x8 bH[8];
  #pragma unroll
  for (int ks = 0; ks < 8; ks++)
    bH[ks] = *(const bf16x8*)(sHw + li*256 + (((ks*4 + g) ^ (li & 7)) << 3));

  // ---- GEMM2: [a;g] = W2 @ h1 + b2 ; gr = x + a*sig(g) -> sHw overlay (16 stages) ----
  for (int mp = 0; mp < 4; mp++){
    f32x4 acc2[8] = {};
    #pragma unroll
    for (int q = 0; q < 4; q++){
      const int s = 8 + mp*4 + q;
      STAGE_ISSUE(s + 1);
      const short* bufc = &sW[s & 1][0];
      #pragma unroll
      for (int ks = 0; ks < 8; ks++)
        #pragma unroll
        for (int mt = 0; mt < 2; mt++){
          bf16x8 afr = *(const bf16x8*)(bufc + (mt*16 + li)*256 + (((ks*4 + g) ^ (li & 7)) << 3));
          acc2[q*2 + mt] = __builtin_amdgcn_mfma_f32_16x16x32_bf16(afr, bH[ks], acc2[q*2 + mt], 0, 0, 0);
        }
      STAGE_WRITE(sW[(s + 1) & 1]);
      __syncthreads();
    }
    #pragma unroll
    for (int q01 = 0; q01 < 2; q01++)
      #pragma unroll
      for (int mt = 0; mt < 2; mt++){
        int m0 = mp*64 + q01*32 + mt*16 + g*4;
        bf16x4 pk;
        #pragma unroll
        for (int r = 0; r < 4; r++){
          float a  = acc2[q01*2 + mt][r] + b2z[m0 + r];
          float gg = acc2[4 + q01*2 + mt][r] + b2z[m0 + r + 256];
          float xv = xb[(size_t)(m0 + r)*1024 + sb + li];
          pk[r] = f2bf(xv + a * sigm(gg));
        }
        *(bf16x4*)(sHw + li*256 + (m0 ^ ((li & 7) << 3))) = pk;
      }
  }

  bf16x8 bG[8];
  #pragma unroll
  for (int ks = 0; ks < 8; ks++)
    bG[ks] = *(const bf16x8*)(sHw + li*256 + (((ks*4 + g) ^ (li & 7)) << 3));

  // ---- GEMM3: tok = Wn @ gr + bn -> global flat [b][512][1024] bf16 (16 stages) ----
  for (int s3 = 0; s3 < 16; s3++){
    const int s = 24 + s3;
    if (s + 1 < 40) STAGE_ISSUE(s + 1);
    const short* bufc = &sW[s & 1][0];
    f32x4 acc[2] = {};
    #pragma unroll
    for (int ks = 0; ks < 8; ks++)
      #pragma unroll
      for (int mt = 0; mt < 2; mt++){
        bf16x8 afr = *(const bf16x8*)(bufc + (mt*16 + li)*256 + (((ks*4 + g) ^ (li & 7)) << 3));
        acc[mt] = __builtin_amdgcn_mfma_f32_16x16x32_bf16(afr, bG[ks], acc[mt], 0, 0, 0);
      }
    #pragma unroll
    for (int mt = 0; mt < 2; mt++)
      #pragma unroll
      for (int r = 0; r < 4; r++){
        int m = s3*32 + mt*16 + g*4 + r;
        tokz[((size_t)b*512 + m)*1024 + sb + li] = f2bf(acc[mt][r] + bnz[m]);
      }
    if (s + 1 < 40){
      STAGE_WRITE(sW[(s + 1) & 1]);
      __syncthreads();
    }
  }
#undef STAGE_ISSUE
#undef STAGE_WRITE
}

// ---------------- flash attention v2: dbuf K/V, 1 barrier/tile, async stage ----------
// Same math/layout/MFMA order as the verified R2 kernel (absmax-identical).
// Pipeline per tile t: barrier -> issue global loads for t+1 into regs (T14)
// -> compute QK^T/softmax/PV from buf[t&1] (setprio around MFMA, T5)
// -> ds_write regs to buf[(t+1)&1]. Buffer-parity: reads of buf[(t+1)&1]
// finished before barrier t, so the post-barrier writes are race-free.
__global__ void k_attn(const short* __restrict__ tok, float* __restrict__ out)
{
  const short* qtok = tok;
  const short* ktok = tok + (size_t)NPIX * 512;
  const short* vtok = tok + (size_t)2 * NPIX * 512;
  const int flat = blockIdx.x;
  const int p = flat >> 6;
  const int g4 = p >> 2, r4 = p & 3;
  // perm = [15,14,13,12, 0,1,2,3, 11,10,9,8, 4,5,6,7] (CU load balance)
  const int qt = (g4 == 0) ? (15 - r4) : (g4 == 1) ? r4 : (g4 == 2) ? (11 - r4) : (4 + r4);
  const int bh = flat & 63;
  const int b = bh >> 3, nh = bh & 7;
  const int tid = threadIdx.x, lane = tid & 63, w = tid >> 6, g = (tid >> 4) & 3, li = tid & 15;
  const int qrow = qt*64 + w*16 + li;       // this lane's query token
  __shared__ short Kl[2][4096];
  __shared__ short Vt[2][4096];             // V transposed: [d][k]
  __shared__ short Pl[4][1024];             // per-wave P [16 q][64 k]

  const short* qptr = qtok + ((size_t)(b*1024 + qrow))*512 + nh*64;
  bf16x8 qf0 = *(const bf16x8*)(qptr + g*8);
  bf16x8 qf1 = *(const bf16x8*)(qptr + 32 + g*8);

  f32x4 accO[4] = {};                       // O^T: 4 d-frags x (16d x 16q)
  float mrun = -1e30f, lrun = 0.f;
  const float scale = 0.04419417382415922f; // 1/sqrt(512)
  short* Pw = &Pl[w][0];

  bf16x8 kreg[2], vreg[2];
#define LOADKV(T)                                                               \
  { const int kb_ = (T)*64;                                                     \
    _Pragma("unroll")                                                           \
    for (int it = 0; it < 2; it++){                                             \
      int i = tid + it*256; int kr = i >> 3, kc = i & 7;                        \
      kreg[it] = *(const bf16x8*)(ktok + ((size_t)(b*1024 + kb_ + kr))*512 + nh*64 + kc*8); } \
    _Pragma("unroll")                                                           \
    for (int it = 0; it < 2; it++){                                             \
      int d0 = w*8 + it*32;                                                     \
      vreg[it] = *(const bf16x8*)(vtok + ((size_t)(b*1024 + kb_ + lane))*512 + nh*64 + d0); } }
#define WRITEKV(NB)                                                             \
  { _Pragma("unroll")                                                           \
    for (int it = 0; it < 2; it++){                                             \
      int i = tid + it*256; int kr = i >> 3, kc = i & 7;                        \
      *(bf16x8*)(&Kl[(NB)][0] + ((kr*64 + kc*8) ^ ((kr & 7) << 3))) = kreg[it]; } \
    _Pragma("unroll")                                                           \
    for (int it = 0; it < 2; it++){                                             \
      int d0 = w*8 + it*32;                                                     \
      _Pragma("unroll")                                                         \
      for (int j = 0; j < 8; j++){                                              \
        int d = d0 + j;                                                         \
        Vt[(NB)][(d*64 + lane) ^ ((d & 7) << 3)] = vreg[it][j]; } } }

  // prologue: tile 0 into buf 0
  LOADKV(0)
  WRITEKV(0)

  for (int kt = 0; kt <= qt; kt++){
    __syncthreads();                        // buf[kt&1] ready; reads of buf[(kt+1)&1] done
    if (kt < qt) LOADKV(kt + 1)             // issue early; consumed after compute
    const short* Kc = &Kl[kt & 1][0];
    const short* Vc = &Vt[kt & 1][0];
    const int kb = kt * 64;

    // S^T frags: 4 x (16 keys x 16 q)
    float pv[16];
    float mt_ = -1e30f;
    const bool diag = (kt == qt);
    __builtin_amdgcn_s_setprio(1);
    #pragma unroll
    for (int kf = 0; kf < 4; kf++){
      f32x4 sa = {};
      const int krow = kf*16 + li;
      bf16x8 ka  = *(const bf16x8*)(Kc + ((krow*64 + g*8) ^ ((krow & 7) << 3)));
      bf16x8 kbf = *(const bf16x8*)(Kc + ((krow*64 + 32 + g*8) ^ ((krow & 7) << 3)));
      sa = __builtin_amdgcn_mfma_f32_16x16x32_bf16(ka, qf0, sa, 0, 0, 0);
      sa = __builtin_amdgcn_mfma_f32_16x16x32_bf16(kbf, qf1, sa, 0, 0, 0);
      #pragma unroll
      for (int r = 0; r < 4; r++){
        const int keyg = kb + kf*16 + g*4 + r;
        float s = sa[r] * scale;
        const bool ok = (!diag) || (keyg < qrow);   // strict causal
        s = ok ? s : -1e30f;
        pv[kf*4 + r] = s;
        mt_ = fmaxf(mt_, s);
      }
    }
    __builtin_amdgcn_s_setprio(0);
    mt_ = fmaxf(mt_, __shfl_xor(mt_, 16));
    mt_ = fmaxf(mt_, __shfl_xor(mt_, 32));
    const float mnew = fmaxf(mrun, mt_);
    const float alpha = __expf(mrun - mnew);
    short pr[16];
    float rs = 0.f;
    #pragma unroll
    for (int i2 = 0; i2 < 16; i2++){
      float p2 = (pv[i2] > -9e29f) ? __expf(pv[i2] - mnew) : 0.f;
      short pb = f2bf(p2);
      pr[i2] = pb;
      rs += bf2f(pb);            // denominator from rounded P (consistent with numerator)
    }
    rs += __shfl_xor(rs, 16);
    rs += __shfl_xor(rs, 32);
    lrun = lrun * alpha + rs;
    mrun = mnew;
    #pragma unroll
    for (int df = 0; df < 4; df++){
      accO[df][0] *= alpha; accO[df][1] *= alpha;
      accO[df][2] *= alpha; accO[df][3] *= alpha;
    }
    // P rows to per-wave LDS (b32 packed pairs; keys 4g+2rp consecutive)
    #pragma unroll
    for (int kf = 0; kf < 4; kf++){
      #pragma unroll
      for (int rp = 0; rp < 2; rp++){
        bf16x2 two;
        two[0] = pr[kf*4 + rp*2];
        two[1] = pr[kf*4 + rp*2 + 1];
        const int key = kf*16 + g*4 + rp*2;
        *(bf16x2*)(Pw + ((li*64 + key) ^ ((li & 7) << 3))) = two;
      }
    }
    // O^T += V^T @ P^T
    __builtin_amdgcn_s_setprio(1);
    #pragma unroll
    for (int kc = 0; kc < 2; kc++){
      bf16x8 pf = *(const bf16x8*)(Pw + ((li*64 + kc*32 + g*8) ^ ((li & 7) << 3)));
      #pragma unroll
      for (int df = 0; df < 4; df++){
        const int dr = df*16 + li;
        bf16x8 vf = *(const bf16x8*)(Vc + ((dr*64 + kc*32 + g*8) ^ ((dr & 7) << 3)));
        accO[df] = __builtin_amdgcn_mfma_f32_16x16x32_bf16(vf, pf, accO[df], 0, 0, 0);
      }
    }
    __builtin_amdgcn_s_setprio(0);
    if (kt < qt) WRITEKV((kt + 1) & 1)      // vmcnt wait inserted here by compiler
  }
#undef LOADKV
#undef WRITEKV
  const float inv = (lrun > 0.f) ? (1.f / lrun) : 0.f;  // row 0: lrun==0 -> zeros (start_mask)
  #pragma unroll
  for (int df = 0; df < 4; df++){
    #pragma unroll
    for (int r = 0; r < 4; r++){
      const int d = df*16 + g*4 + r;
      out[((size_t)b*512 + nh*64 + d)*1024 + qrow] = accO[df][r] * inv;
    }
  }
}

extern "C" void kernel_launch(void* const* d_in, const int* in_sizes, int n_in,
                              void* d_out, int out_size, void* d_ws, size_t ws_size,
                              hipStream_t stream)
{
  (void)in_sizes; (void)n_in; (void)out_size; (void)ws_size;
  const float* query = (const float*)d_in[0];
  const float* key   = (const float*)d_in[1];
  const float* w1[3] = {(const float*)d_in[2],  (const float*)d_in[8],  (const float*)d_in[14]};
  const float* b1[3] = {(const float*)d_in[3],  (const float*)d_in[9],  (const float*)d_in[15]};
  const float* w2[3] = {(const float*)d_in[4],  (const float*)d_in[10], (const float*)d_in[16]};
  const float* b2[3] = {(const float*)d_in[5],  (const float*)d_in[11], (const float*)d_in[17]};
  const float* wn[3] = {(const float*)d_in[6],  (const float*)d_in[12], (const float*)d_in[18]};
  const float* bn[3] = {(const float*)d_in[7],  (const float*)d_in[13], (const float*)d_in[19]};

  char* ws = (char*)d_ws;
  short* wsW = (short*)(ws + OFF_W);
  short* tok = (short*)(ws + OFF_TOK);
  float* out = (float*)d_out;

  k_prep<<<dim3(960), dim3(256), 0, stream>>>(w1[0], w2[0], wn[0],
                                              w1[1], w2[1], wn[1],
                                              w1[2], w2[2], wn[2], wsW);
  k_branch<<<dim3(128, 3), dim3(256), 0, stream>>>(wsW, query, key,
                                                   b1[0], b1[1], b1[2],
                                                   b2[0], b2[1], b2[2],
                                                   bn[0], bn[1], bn[2], tok);
  k_attn<<<dim3(1024), dim3(256), 0, stream>>>(tok, out);
}